// Round 2
// baseline (374.213 us; speedup 1.0000x reference)
//
#include <hip/hip_runtime.h>

using u32 = unsigned int;
using u64 = unsigned long long;

// ---- workspace layout (u32 words) ----
#define H1_BINS 4096   // bits [30:19]
#define H2_BINS 2048   // bits [18:8]
#define H3_BINS 256    // bits [7:0]
#define H1_OFF  0
#define H2_OFF  (H1_OFF + 2 * H1_BINS)        // 8192
#define H3_OFF  (H2_OFF + 2 * H2_BINS)        // 12288
#define SEL_OFF (H3_OFF + 2 * H3_BINS)        // 12800
#define SEL_WORDS 16
// sel: 0=p1, 1=p2, 2=G1, 3=t, 4=R, 5=G12
#define CTR_OFF  (SEL_OFF + 2 * SEL_WORDS)    // 12832 : 8 last-block counters
#define GCNT_OFF (CTR_OFF + 8)                // 12840 : candidate counts
#define ECNT_OFF (GCNT_OFF + 2)               // 12842 : eq counts
#define ZERO_WORDS (ECNT_OFF + 2)             // 12844
#define EQ_OFF   12848
#define EQ_CAP   4096
#define CAND_OFF (EQ_OFF + 2 * EQ_CAP)        // 21040 (×4B = 8B-aligned)
#define GCAP     (1u << 21)                   // 2M candidates per matrix (10× margin)
#define SCAP     2048                         // per-block LDS staging

__device__ __forceinline__ u32 absbits(u32 x) { return x & 0x7FFFFFFFu; }
__device__ __forceinline__ u32 aload(u32* p)  { return atomicAdd(p, 0u); }  // coherent read

// suffix-scan select over a global histogram; results into (shared) temps.
// Finds bin b s.t. count-above(b) < Krem <= count-above(b) + hist[b].
template<int BINS>
__device__ void block_select(u32* hist, u32 Krem, u32* selBin, u32* selAbove) {
    __shared__ u32 sh[256];
    constexpr int C = BINS / 256;
    u32 loc[C];
    const int tid = threadIdx.x;
    const int base = tid * C;
    u32 s = 0;
    for (int i = 0; i < C; i++) { loc[i] = aload(&hist[base + i]); s += loc[i]; }
    sh[tid] = s;
    __syncthreads();
    if (tid == 0) {
        u32 run = 0;
        for (int i = 255; i >= 0; i--) { u32 x = sh[i]; sh[i] = run; run += x; }
    }
    __syncthreads();
    u32 running = sh[tid];
    for (int b = C - 1; b >= 0; b--) {
        u32 c = loc[b];
        if (running < Krem && running + c >= Krem) { *selBin = (u32)(base + b); *selAbove = running; }
        running += c;
    }
}

// ---------- pass A: 12-bit histogram + fused select (last block) ----------
__global__ void k_hist1(const float* __restrict__ in0, const float* __restrict__ in1,
                        int n0, int n1, u32* __restrict__ ws, int K0, int K1) {
    const int m = blockIdx.y;
    const u32* in = (const u32*)(m ? in1 : in0);
    const int n = m ? n1 : n0;
    const int n4 = n >> 2;
    u32* g = ws + H1_OFF + m * H1_BINS;
    __shared__ u32 h[2][H1_BINS];   // wave-pair privatized copies (32 KB)
    for (int i = threadIdx.x; i < H1_BINS; i += blockDim.x) { h[0][i] = 0; h[1][i] = 0; }
    __syncthreads();
    u32* hp = h[threadIdx.x >> 7];
    const uint4* v = (const uint4*)in;
    const int stride = gridDim.x * blockDim.x;
    for (int i = blockIdx.x * blockDim.x + threadIdx.x; i < n4; i += stride) {
        uint4 x = v[i];
        atomicAdd(&hp[absbits(x.x) >> 19], 1u);
        atomicAdd(&hp[absbits(x.y) >> 19], 1u);
        atomicAdd(&hp[absbits(x.z) >> 19], 1u);
        atomicAdd(&hp[absbits(x.w) >> 19], 1u);
    }
    if (blockIdx.x == 0 && (int)threadIdx.x < (n & 3))
        atomicAdd(&hp[absbits(in[n4 * 4 + threadIdx.x]) >> 19], 1u);
    __syncthreads();
    for (int i = threadIdx.x; i < H1_BINS; i += blockDim.x) {
        u32 t = h[0][i] + h[1][i];
        if (t) atomicAdd(&g[i], t);
    }
    __syncthreads();
    __shared__ bool last;
    if (threadIdx.x == 0) {
        __threadfence();
        last = (atomicAdd(&ws[CTR_OFF + m], 1u) == gridDim.x - 1);
    }
    __syncthreads();
    if (last) {
        __shared__ u32 tb, ta;
        const u32 K = (u32)(m ? K1 : K0);
        block_select<H1_BINS>(g, K, &tb, &ta);
        __syncthreads();
        if (threadIdx.x == 0) {
            u32* sel = ws + SEL_OFF + m * SEL_WORDS;
            sel[0] = tb;   // p1
            sel[2] = ta;   // G1 = count strictly above bin p1
        }
    }
}

// ---------- pass B: write decided mask, compact threshold-bin candidates ----------
__global__ void k_mask_compact(const float* __restrict__ in0, const float* __restrict__ in1,
                               float* __restrict__ out0, float* __restrict__ out1,
                               int n0, int n1, u32* __restrict__ ws) {
    const int m = blockIdx.y;
    const u32* in = (const u32*)(m ? in1 : in0);
    float* out = m ? out1 : out0;
    const int n = m ? n1 : n0;
    const int n4 = n >> 2;
    const u32 p1 = ws[SEL_OFF + m * SEL_WORDS + 0];
    u32* gcnt = &ws[GCNT_OFF + m];
    uint2* cand = (uint2*)(ws + CAND_OFF) + (size_t)m * GCAP;

    __shared__ u32 scnt;
    __shared__ u32 gbase;
    __shared__ uint2 stage[SCAP];
    if (threadIdx.x == 0) scnt = 0;
    __syncthreads();

    const u32 lane = threadIdx.x & 63u;
    const u64 lmask = (1ull << lane) - 1ull;

    auto handle = [&](u32 a, u32 idx) {
        bool pred = ((a >> 19) == p1);
        u64 mk = __ballot(pred);
        if (mk) {
            u32 cnt = (u32)__popcll(mk);
            int leader = __ffsll((unsigned long long)mk) - 1;
            u32 base = 0;
            if ((int)lane == leader) base = atomicAdd(&scnt, cnt);
            base = __shfl(base, leader);
            if (pred) {
                u32 pos = base + (u32)__popcll(mk & lmask);
                if (pos < SCAP) stage[pos] = make_uint2(a, idx);
                else { u32 gp = atomicAdd(gcnt, 1u); if (gp < GCAP) cand[gp] = make_uint2(a, idx); }
            }
        }
    };

    const uint4* v = (const uint4*)in;
    float4* o = (float4*)out;
    const int stride = gridDim.x * blockDim.x;
    for (int i = blockIdx.x * blockDim.x + threadIdx.x; i < n4; i += stride) {
        uint4 x = v[i];
        u32 a0 = absbits(x.x), a1 = absbits(x.y), a2 = absbits(x.z), a3 = absbits(x.w);
        float4 r;
        r.x = ((a0 >> 19) > p1) ? 1.0f : 0.0f;
        r.y = ((a1 >> 19) > p1) ? 1.0f : 0.0f;
        r.z = ((a2 >> 19) > p1) ? 1.0f : 0.0f;
        r.w = ((a3 >> 19) > p1) ? 1.0f : 0.0f;
        o[i] = r;
        handle(a0, (u32)(4 * i + 0));
        handle(a1, (u32)(4 * i + 1));
        handle(a2, (u32)(4 * i + 2));
        handle(a3, (u32)(4 * i + 3));
    }
    if (blockIdx.x == 0 && (int)threadIdx.x < (n & 3)) {
        int idx = n4 * 4 + threadIdx.x;
        u32 a = absbits(in[idx]);
        out[idx] = ((a >> 19) > p1) ? 1.0f : 0.0f;
        handle(a, (u32)idx);
    }
    __syncthreads();
    if (threadIdx.x == 0) {
        u32 c = scnt < SCAP ? scnt : SCAP;
        gbase = atomicAdd(gcnt, c);
    }
    __syncthreads();
    u32 c = scnt < SCAP ? scnt : SCAP;
    for (u32 j = threadIdx.x; j < c; j += blockDim.x) {
        u32 p = gbase + j;
        if (p < GCAP) cand[p] = stage[j];
    }
}

// ---------- pass C2: 11-bit histogram over candidates + fused select ----------
__global__ void k_cand_hist2(u32* __restrict__ ws, int K0, int K1) {
    const int m = blockIdx.y;
    u32 cnt0 = ws[GCNT_OFF + m];
    const u32 cnt = cnt0 < GCAP ? cnt0 : GCAP;
    const uint2* cand = (const uint2*)(ws + CAND_OFF) + (size_t)m * GCAP;
    u32* g = ws + H2_OFF + m * H2_BINS;
    __shared__ u32 h[H2_BINS];
    for (int i = threadIdx.x; i < H2_BINS; i += blockDim.x) h[i] = 0;
    __syncthreads();
    const u32 stride = gridDim.x * blockDim.x;
    for (u32 i = blockIdx.x * blockDim.x + threadIdx.x; i < cnt; i += stride)
        atomicAdd(&h[(cand[i].x >> 8) & 0x7FFu], 1u);
    __syncthreads();
    for (int i = threadIdx.x; i < H2_BINS; i += blockDim.x)
        if (h[i]) atomicAdd(&g[i], h[i]);
    __syncthreads();
    __shared__ bool last;
    if (threadIdx.x == 0) {
        __threadfence();
        last = (atomicAdd(&ws[CTR_OFF + 2 + m], 1u) == gridDim.x - 1);
    }
    __syncthreads();
    if (last) {
        u32* sel = ws + SEL_OFF + m * SEL_WORDS;
        const u32 K = (u32)(m ? K1 : K0);
        const u32 G1 = sel[2];
        __shared__ u32 tb, ta;
        block_select<H2_BINS>(g, K - G1, &tb, &ta);
        __syncthreads();
        if (threadIdx.x == 0) { sel[1] = tb; sel[5] = G1 + ta; }
    }
}

// ---------- pass C3: 8-bit histogram over prefix-matched candidates + fused select ----------
__global__ void k_cand_hist3(u32* __restrict__ ws, int K0, int K1) {
    const int m = blockIdx.y;
    u32 cnt0 = ws[GCNT_OFF + m];
    const u32 cnt = cnt0 < GCAP ? cnt0 : GCAP;
    const uint2* cand = (const uint2*)(ws + CAND_OFF) + (size_t)m * GCAP;
    u32* sel = ws + SEL_OFF + m * SEL_WORDS;
    const u32 p1 = sel[0], p2 = sel[1];
    const u32 pre20 = (p1 << 11) | p2;
    u32* g = ws + H3_OFF + m * H3_BINS;
    __shared__ u32 h[H3_BINS];
    for (int i = threadIdx.x; i < H3_BINS; i += blockDim.x) h[i] = 0;
    __syncthreads();
    const u32 stride = gridDim.x * blockDim.x;
    for (u32 i = blockIdx.x * blockDim.x + threadIdx.x; i < cnt; i += stride) {
        u32 a = cand[i].x;
        if ((a >> 8) == pre20) atomicAdd(&h[a & 0xFFu], 1u);
    }
    __syncthreads();
    for (int i = threadIdx.x; i < H3_BINS; i += blockDim.x)
        if (h[i]) atomicAdd(&g[i], h[i]);
    __syncthreads();
    __shared__ bool last;
    if (threadIdx.x == 0) {
        __threadfence();
        last = (atomicAdd(&ws[CTR_OFF + 4 + m], 1u) == gridDim.x - 1);
    }
    __syncthreads();
    if (last) {
        const u32 K = (u32)(m ? K1 : K0);
        const u32 Krem3 = K - sel[5];
        __shared__ u32 tb, ta;
        block_select<H3_BINS>(g, Krem3, &tb, &ta);
        __syncthreads();
        if (threadIdx.x == 0) {
            sel[3] = (p1 << 19) | (p2 << 8) | tb;  // threshold bits t
            sel[4] = Krem3 - ta;                   // R = ones among ties
        }
    }
}

// ---------- pass F: finalize candidates (+ fused tie resolution in last block) ----------
__global__ void k_final(float* __restrict__ out0, float* __restrict__ out1, u32* __restrict__ ws) {
    const int m = blockIdx.y;
    float* out = m ? out1 : out0;
    u32 cnt0 = ws[GCNT_OFF + m];
    const u32 cnt = cnt0 < GCAP ? cnt0 : GCAP;
    const uint2* cand = (const uint2*)(ws + CAND_OFF) + (size_t)m * GCAP;
    u32* sel = ws + SEL_OFF + m * SEL_WORDS;
    const u32 t = sel[3];
    const u32 stride = gridDim.x * blockDim.x;
    for (u32 i = blockIdx.x * blockDim.x + threadIdx.x; i < cnt; i += stride) {
        uint2 cv = cand[i];
        if (cv.x > t) out[cv.y] = 1.0f;
        else if (cv.x == t) {
            u32 e = atomicAdd(&ws[ECNT_OFF + m], 1u);
            if (e < EQ_CAP) atomicExch(&ws[EQ_OFF + m * EQ_CAP + e], cv.y);  // device-coherent store
        }
    }
    __shared__ bool last;
    if (threadIdx.x == 0) {
        __threadfence();
        last = (atomicAdd(&ws[CTR_OFF + 6 + m], 1u) == gridDim.x - 1);
    }
    __syncthreads();
    if (last) {
        u32 E0 = aload(&ws[ECNT_OFF + m]);
        u32 E = E0 < EQ_CAP ? E0 : EQ_CAP;
        const u32 R = sel[4];
        __shared__ u32 eqs[EQ_CAP];
        for (u32 e = threadIdx.x; e < E; e += blockDim.x) eqs[e] = aload(&ws[EQ_OFF + m * EQ_CAP + e]);
        __syncthreads();
        for (u32 e = threadIdx.x; e < E; e += blockDim.x) {
            u32 idx = eqs[e];
            u32 c = 0;
            for (u32 e2 = 0; e2 < E; e2++) c += (eqs[e2] > idx) ? 1u : 0u;
            if (c < R) out[idx] = 1.0f;  // R tied elements with largest indices get 1 (stable argsort)
        }
    }
}

extern "C" void kernel_launch(void* const* d_in, const int* in_sizes, int n_in,
                              void* d_out, int out_size, void* d_ws, size_t ws_size,
                              hipStream_t stream) {
    const float* in0 = (const float*)d_in[0];
    const float* in1 = (const float*)d_in[1];
    const int n0 = in_sizes[0];
    const int n1 = in_sizes[1];
    float* out0 = (float*)d_out;
    float* out1 = out0 + n0;
    u32* ws = (u32*)d_ws;

    // Faithful to int((1.0 - k) * n): j = 15,099,494 for n = 16,777,216
    const double k = 0.1;
    const int K0 = n0 - (int)((1.0 - k) * (double)n0);
    const int K1 = n1 - (int)((1.0 - k) * (double)n1);

    hipMemsetAsync(ws, 0, ZERO_WORDS * sizeof(u32), stream);
    k_hist1<<<dim3(1024, 2), 256, 0, stream>>>(in0, in1, n0, n1, ws, K0, K1);
    k_mask_compact<<<dim3(1024, 2), 256, 0, stream>>>(in0, in1, out0, out1, n0, n1, ws);
    k_cand_hist2<<<dim3(64, 2), 256, 0, stream>>>(ws, K0, K1);
    k_cand_hist3<<<dim3(64, 2), 256, 0, stream>>>(ws, K0, K1);
    k_final<<<dim3(64, 2), 256, 0, stream>>>(out0, out1, ws);
}